// Round 1
// baseline (88.892 us; speedup 1.0000x reference)
//
#include <hip/hip_runtime.h>
#include <math.h>

// DiffRenderer: BS=4, IMG=64, D_STEPS=64, D_SH=61, H1=128
// Inputs: z_shape(4,61), z_extr(4,5), W1(64,128), b1(128), W2(128,1), b2(1)
// Output: depth_pred (4*64*64) ++ occ (4*64*64), fp32

#define N_RAYS (4 * 64 * 64)

// ---------------------------------------------------------------------------
// Kernel 1: cvec[b][h] = b1[h] + sum_f z_shape[b,f] * W1[3+f, h]   (4 x 128)
// ---------------------------------------------------------------------------
__global__ __launch_bounds__(512) void precompute_cvec(
    const float* __restrict__ z_shape,   // (4,61)
    const float* __restrict__ W1,        // (64,128) row-major
    const float* __restrict__ b1,        // (128)
    float* __restrict__ cvec)            // (4,128)
{
    int tid = blockIdx.x * blockDim.x + threadIdx.x;
    if (tid >= 4 * 128) return;
    int b = tid >> 7;
    int h = tid & 127;
    float acc = b1[h];
    #pragma unroll
    for (int f = 0; f < 61; ++f)
        acc = fmaf(z_shape[b * 61 + f], W1[(3 + f) * 128 + h], acc);
    cvec[tid] = acc;
}

// ---------------------------------------------------------------------------
// Kernel 2: one wave (64 lanes) per ray; lane = depth step k.
// ---------------------------------------------------------------------------
__global__ __launch_bounds__(256) void render_kernel(
    const float* __restrict__ z_extr,    // (4,5): scale, tx, ty, tz, alpha
    const float* __restrict__ W1,        // (64,128)
    const float* __restrict__ W2,        // (128,1)
    const float* __restrict__ b2,        // (1)
    const float* __restrict__ cvec,      // (4,128)
    float* __restrict__ out)             // depth[16384] then occ[16384]
{
    const int lane = threadIdx.x & 63;
    // force wave-uniformity so batch-dependent loads become scalar loads
    const int wave = __builtin_amdgcn_readfirstlane((int)(threadIdx.x >> 6));
    const int ray  = blockIdx.x * 4 + wave;       // 0..16383
    const int b    = ray >> 12;                   // batch
    const int rem  = ray & 4095;
    const int yi   = rem >> 6;                    // pixel row (y)
    const int xj   = rem & 63;                    // pixel col (x)

    // per-batch extrinsics (scalar loads)
    const float scale = z_extr[b * 5 + 0];
    const float tx    = z_extr[b * 5 + 1];
    const float ty    = z_extr[b * 5 + 2];
    const float tz    = z_extr[b * 5 + 3];
    const float alpha = z_extr[b * 5 + 4];

    const float a  = 3.14159274101257324f * alpha;   // fp32(pi) * alpha
    const float ca = cosf(a);
    const float sa = sinf(a);
    const float s_obj = 1.0f / scale;                // reference: 1/z_extr[:,0]
    const float s_inv = 1.0f / s_obj;                // reference: 1/s_obj
    const float T = tz + 2.5f;                       // bb_depth (mean of 9 bbox z's)

    // depth sample for this lane
    const float step = 2.0f / 63.0f;
    const float zk  = -1.0f + (float)lane * step;
    const float Z   = zk * s_inv + T;                // camera-space depth
    // Zc at k+1 (for d2); lane 63 value never used as a crossing start
    const float zk1 = -1.0f + (float)(lane + 1) * step;
    const float Z1  = zk1 * s_inv + T;

    // pixel -> camera ray direction via K_inv: [(x-c)/f, (y-c)/f, 1]
    const float kf  = 1.0f / 70.0f;
    const float kc  = -(31.5f / 70.0f);
    const float u = fmaf((float)xj, kf, kc);
    const float v = fmaf((float)yi, kf, kc);

    // world point = depth * K_inv*p - t  (R_t = I, t = [0,0,2.5])
    // object coords = s_obj * R_obj @ (world - t_obj)
    const float qx = Z * u - tx;
    const float qy = Z * v - ty;
    const float qz = (Z - 2.5f) - tz;
    const float X0 = s_obj * (ca * qx - sa * qy);
    const float X1 = s_obj * (sa * qx + ca * qy);
    const float X2 = s_obj * qz;

    // MLP: v = b2 + sum_j relu(X0*W1[0,j] + X1*W1[1,j] + X2*W1[2,j] + cvec[j]) * W2[j]
    const float4* __restrict__ w0 = (const float4*)(W1);
    const float4* __restrict__ w1 = (const float4*)(W1 + 128);
    const float4* __restrict__ w2 = (const float4*)(W1 + 256);
    const float4* __restrict__ wc = (const float4*)(cvec + b * 128);
    const float4* __restrict__ wo = (const float4*)(W2);

    float acc = b2[0];
    #pragma unroll 8
    for (int q = 0; q < 32; ++q) {
        const float4 a0 = w0[q];
        const float4 a1 = w1[q];
        const float4 a2 = w2[q];
        const float4 cc = wc[q];
        const float4 ww = wo[q];
        float h0 = fmaxf(fmaf(X0, a0.x, fmaf(X1, a1.x, fmaf(X2, a2.x, cc.x))), 0.0f);
        float h1 = fmaxf(fmaf(X0, a0.y, fmaf(X1, a1.y, fmaf(X2, a2.y, cc.y))), 0.0f);
        float h2 = fmaxf(fmaf(X0, a0.z, fmaf(X1, a1.z, fmaf(X2, a2.z, cc.z))), 0.0f);
        float h3 = fmaxf(fmaf(X0, a0.w, fmaf(X1, a1.w, fmaf(X2, a2.w, cc.w))), 0.0f);
        acc = fmaf(h0, ww.x, acc);
        acc = fmaf(h1, ww.y, acc);
        acc = fmaf(h2, ww.z, acc);
        acc = fmaf(h3, ww.w, acc);
    }
    const float sdf = tanhf(acc);

    // zero-crossing detection along depth (lane axis)
    const unsigned long long mask  = __ballot(sdf > 0.0f);
    const unsigned long long cross = mask & ~(mask >> 1) & 0x7fffffffffffffffULL;

    const bool isC = (cross >> lane) & 1ULL;
    const float sdf_next = __shfl_down(sdf, 1, 64);

    float d1 = isC ? Z        : 100.0f;
    float d2 = isC ? Z1       : 100.0f;
    float s1 = isC ? sdf      : 0.0f;
    float s2 = isC ? sdf_next : 0.0f;

    #pragma unroll
    for (int m = 1; m < 64; m <<= 1) {
        d1 = fminf(d1, __shfl_xor(d1, m, 64));
        d2 = fminf(d2, __shfl_xor(d2, m, 64));
        s1 += __shfl_xor(s1, m, 64);
        s2 += __shfl_xor(s2, m, 64);
    }

    if (lane == 0) {
        float occ = (cross != 0ULL) ? 1.0f : 0.0f;
        float depth = 0.0f;
        if (cross != 0ULL)
            depth = d1 - s1 / (s2 - s1 - 1e-6f) * (d2 - d1);
        out[ray]          = depth;   // depth_pred, (b, yi, xj) == ray
        out[N_RAYS + ray] = occ;     // occ
    }
}

extern "C" void kernel_launch(void* const* d_in, const int* in_sizes, int n_in,
                              void* d_out, int out_size, void* d_ws, size_t ws_size,
                              hipStream_t stream) {
    const float* z_shape = (const float*)d_in[0];   // (4,61)
    const float* z_extr  = (const float*)d_in[1];   // (4,5)
    const float* W1      = (const float*)d_in[2];   // (64,128)
    const float* b1      = (const float*)d_in[3];   // (128)
    const float* W2      = (const float*)d_in[4];   // (128,1)
    const float* b2      = (const float*)d_in[5];   // (1)
    float* out  = (float*)d_out;
    float* cvec = (float*)d_ws;                     // 4*128 floats scratch

    precompute_cvec<<<1, 512, 0, stream>>>(z_shape, W1, b1, cvec);
    render_kernel<<<N_RAYS / 4, 256, 0, stream>>>(z_extr, W1, W2, b2, cvec, out);
}